// Round 7
// baseline (27327.216 us; speedup 1.0000x reference)
//
#include <hip/hip_runtime.h>
#include <hip/hip_bf16.h>

typedef __hip_bfloat16 bf16;

// flag f: 0 = bf16, 1 = fp32
static __device__ __forceinline__ float ldm(const void* p, long i, int f){
  return f ? ((const float*)p)[i] : __bfloat162float(((const bf16*)p)[i]);
}
static __device__ __forceinline__ void stm(void* p, long i, int f, float v){
  if(f) ((float*)p)[i] = v; else ((bf16*)p)[i] = __float2bfloat16(v);
}

// ---------------- input dtype detector (bit-level correct) ----------------
__global__ void k_detect(const void* __restrict__ w, int* __restrict__ mode){
  if(blockIdx.x == 0 && threadIdx.x == 0){
    const unsigned int* u = (const unsigned int*)w;
    int saneLo = 0;
    for(int i = 0; i < 64; i++){
      unsigned short lo = (unsigned short)(u[i] & 0xFFFFu);
      unsigned int fw = ((unsigned int)lo) << 16;
      float v; __builtin_memcpy(&v, &fw, 4);
      float a = fabsf(v);
      if(a > 1e-7f && a < 100.f) saneLo++;
    }
    *mode = (saneLo >= 48) ? 0 : 1;   // 0 = bf16, 1 = fp32
  }
}

// ---------------- SAGE weight transpose: wT[c][o] = w[o][c] ----------------
__global__ void k_wtrans(const void* __restrict__ w, float* __restrict__ wT,
                         const int* __restrict__ dmode, int C){
  int idx = blockIdx.x * 256 + threadIdx.x;
  if(idx >= C * C) return;
  int dm = *dmode;
  int o = idx % C, c = idx / C;
  wT[idx] = ldm(w, (long)o * C + c, dm);
}

// ---------------- convT weight transpose: wT[(ci*9+k)*Cout+co] = w[(ci*Cout+co)*9+k] ----------------
__global__ void k_wtrans2(const void* __restrict__ w, float* __restrict__ wT,
                          const int* __restrict__ dmode, int Cin, int Cout){
  int idx = blockIdx.x * 256 + threadIdx.x;
  if(idx >= Cin * Cout * 9) return;
  int dm = *dmode;
  int co = idx % Cout; int t = idx / Cout; int k = t % 9; int ci = t / 9;
  wT[idx] = ldm(w, ((long)ci * Cout + co) * 9 + k, dm);
}

// ---------------- direct conv 3x3, pad 1, stride S ----------------
template<int S>
__global__ void k_conv3x3(const void* __restrict__ in, long in_off, int fin_sel,
                          const void* __restrict__ w, const void* __restrict__ bias,
                          void* __restrict__ out, int fout,
                          const int* __restrict__ dmode,
                          int B, int Cin, int Hin, int Win, int Cout, int Hout, int Wout)
{
  long idx = (long)blockIdx.x * 256 + threadIdx.x;
  long total = (long)B * Cout * Hout * Wout;
  if(idx >= total) return;
  int dm = *dmode;
  int fin = (fin_sel == 2) ? dm : fin_sel;
  int wo = (int)(idx % Wout); long t = idx / Wout;
  int ho = (int)(t % Hout);   t /= Hout;
  int co = (int)(t % Cout);   int b = (int)(t / Cout);
  float acc = ldm(bias, co, dm);
  int hbase = ho * S - 1, wbase = wo * S - 1;
  long wbi = (long)co * Cin * 9;
  long ibase = in_off + (long)b * Cin * Hin * Win;
  for(int ci = 0; ci < Cin; ci++){
    long ip = ibase + (long)ci * Hin * Win;
    long wp = wbi + (long)ci * 9;
    #pragma unroll
    for(int kh = 0; kh < 3; kh++){
      int hi = hbase + kh;
      if((unsigned)hi >= (unsigned)Hin) continue;
      long rp = ip + (long)hi * Win;
      #pragma unroll
      for(int kw = 0; kw < 3; kw++){
        int wi = wbase + kw;
        if((unsigned)wi >= (unsigned)Win) continue;
        acc += ldm(in, rp + wi, fin) * ldm(w, wp + kh*3 + kw, dm);
      }
    }
  }
  stm(out, idx, fout, acc);
}

// ---------------- InstanceNorm (affine=False) + PReLU, in place ----------------
__global__ void k_inorm_prelu(void* __restrict__ x, int f, int HW,
                              const void* __restrict__ a, const int* __restrict__ dmode)
{
  int dm = *dmode;
  long base = (long)blockIdx.x * HW;
  float s = 0.f, s2 = 0.f;
  for(int i = threadIdx.x; i < HW; i += 256){ float v = ldm(x, base + i, f); s += v; s2 += v*v; }
  __shared__ float sh[256], sh2[256];
  sh[threadIdx.x] = s; sh2[threadIdx.x] = s2; __syncthreads();
  for(int off = 128; off > 0; off >>= 1){
    if(threadIdx.x < off){ sh[threadIdx.x] += sh[threadIdx.x+off]; sh2[threadIdx.x] += sh2[threadIdx.x+off]; }
    __syncthreads();
  }
  float mean = sh[0] / HW;
  float var  = sh2[0] / HW - mean * mean;
  float inv  = rsqrtf(fmaxf(var, 0.f) + 1e-5f);
  float alpha = ldm(a, 0, dm);
  for(int i = threadIdx.x; i < HW; i += 256){
    float v = (ldm(x, base + i, f) - mean) * inv;
    stm(x, base + i, f, v >= 0.f ? v : alpha * v);
  }
}

// ---------------- transpose [B,C,N] -> [B,N,C] (fp32) ----------------
__global__ void k_transpose(const float* __restrict__ in, float* __restrict__ out, int B, int C, int N){
  long idx = (long)blockIdx.x * 256 + threadIdx.x;
  long total = (long)B * C * N; if(idx >= total) return;
  int c = (int)(idx % C); long t = idx / C; int n = (int)(t % N); int b = (int)(t / N);
  out[idx] = in[((long)b * C + c) * N + n];
}

// ---------------- degree ----------------
__global__ void k_deg(const int* __restrict__ tgt, float* __restrict__ deg, int E){
  int e = blockIdx.x * 256 + threadIdx.x;
  if(e < E) atomicAdd(&deg[tgt[e]], 1.0f);
}

// ---------------- scatter add: agg[b,tgt,c] += x[b,src,c]  ([B,N,C] fp32) ----------------
__global__ void k_scatter(const float* __restrict__ xT, const int* __restrict__ src,
                          const int* __restrict__ tgt, float* __restrict__ agg,
                          int E, int C, int N, int B)
{
  int t = blockIdx.x * 256 + threadIdx.x;
  if(t >= E * C) return;
  int c = t % C; int e = t / C;
  int s = src[e], d = tgt[e];
  for(int b = 0; b < B; b++){
    atomicAdd(&agg[((long)b * N + d) * C + c], xT[((long)b * N + s) * C + c]);
  }
}

// ---------------- SAGE as tiled GEMM ----------------
#define TN 5
__global__ void k_sage2(const float* __restrict__ xT, const float* __restrict__ agg,
                        const float* __restrict__ deg,
                        const float* __restrict__ wlT, const float* __restrict__ wrT,
                        const void* __restrict__ bl,
                        float* __restrict__ out, const int* __restrict__ dmode,
                        int B, int N, int C, int transpose_out)
{
  int o  = threadIdx.x;
  int n0 = blockIdx.x * TN;
  int b  = blockIdx.y;
  __shared__ float sX[TN][256];
  __shared__ float sA[TN][256];
  #pragma unroll
  for(int j = 0; j < TN; j++){
    int n = n0 + j;
    float dinv = 1.0f / fmaxf(deg[n], 1.0f);
    long base = ((long)b * N + n) * C;
    sX[j][o] = xT[base + o];
    sA[j][o] = agg[base + o] * dinv;
  }
  __syncthreads();
  int dm = *dmode;
  float bv = ldm(bl, o, dm);
  float acc[TN];
  #pragma unroll
  for(int j = 0; j < TN; j++) acc[j] = bv;
  #pragma unroll 4
  for(int c = 0; c < 256; c++){
    float wlv = wlT[(long)c * 256 + o];
    float wrv = wrT[(long)c * 256 + o];
    #pragma unroll
    for(int j = 0; j < TN; j++){
      acc[j] += sA[j][c] * wlv + sX[j][c] * wrv;
    }
  }
  #pragma unroll
  for(int j = 0; j < TN; j++){
    int n = n0 + j;
    float v = fmaxf(acc[j], 0.f);
    if(transpose_out) out[((long)b * C + o) * N + n] = v;
    else              out[((long)b * N + n) * C + o] = v;
  }
}

// ---------------- ConvTranspose2d k=3 s=2 p=1 op=1 — row-GEMM, parity quad ----------------
// Block = CTO co-lanes x G groups (CTO == Cout). Block owns input row pair
// (i, i+1) x G*8 consecutive cols. Per ci: 9 lane-coalesced fp32 weight loads
// (pre-transposed wT[(ci*9+k)*Cout+co], L2-resident) + 18 LDS broadcasts +
// 72 FMA. Staging: full consecutive rows -> dense cache lines.
template<int CTO, int G, int CC>
__global__ void k_convT3(const void* __restrict__ inA, int fA, int C1,
                         const void* __restrict__ inB, int fB, int C2,
                         const float* __restrict__ wT, const void* __restrict__ bias,
                         void* __restrict__ out, long out_off, int fout_sel,
                         const int* __restrict__ dmode,
                         int Hin, int Win, int ntj)
{
  const int SPAN = G*8 + 1;
  __shared__ float sX[CC][2][SPAN];
  int tid = threadIdx.x;
  int co = tid % CTO, g = tid / CTO;
  int i  = blockIdx.x / ntj, tj = blockIdx.x % ntj;
  int j0 = tj * (G*8);
  int b  = blockIdx.z;
  int dm = *dmode;
  const int Cout = CTO;
  int Cin = C1 + C2;
  int Wout = 2*Win;

  float acc[8][4];
  #pragma unroll
  for(int p = 0; p < 8; p++){ acc[p][0]=0.f; acc[p][1]=0.f; acc[p][2]=0.f; acc[p][3]=0.f; }

  for(int ci0 = 0; ci0 < Cin; ci0 += CC){
    for(int e = tid; e < CC*2*SPAN; e += 256){
      int s = e / (2*SPAN); int rem = e % (2*SPAN);
      int row = rem / SPAN, col = rem % SPAN;
      int ci = ci0 + s;
      int ii = i + row, jj = j0 + col;
      float v = 0.f;
      if(ii < Hin && jj < Win){
        v = (ci < C1) ? ldm(inA, ((long)b*C1 + ci)*Hin*Win + (long)ii*Win + jj, fA)
                      : ldm(inB, ((long)b*C2 + (ci-C1))*Hin*Win + (long)ii*Win + jj, fB);
      }
      sX[s][row][col] = v;
    }
    __syncthreads();
    for(int s = 0; s < CC; s++){
      int ci = ci0 + s;
      float wv[9];
      #pragma unroll
      for(int k = 0; k < 9; k++) wv[k] = wT[((long)ci*9 + k)*Cout + co];
      float x0[9], x1[9];
      #pragma unroll
      for(int c = 0; c < 9; c++){ x0[c] = sX[s][0][g*8 + c]; x1[c] = sX[s][1][g*8 + c]; }
      #pragma unroll
      for(int p = 0; p < 8; p++){
        float a00 = x0[p], a01 = x0[p+1], a10 = x1[p], a11 = x1[p+1];
        acc[p][0] += a00*wv[4];
        acc[p][1] += a00*wv[5] + a01*wv[3];
        acc[p][2] += a00*wv[7] + a10*wv[1];
        acc[p][3] += a00*wv[8] + a01*wv[6] + a10*wv[2] + a11*wv[0];
      }
    }
    __syncthreads();
  }

  float bv = ldm(bias, co, dm);
  int fout = (fout_sel == 2) ? dm : fout_sel;
  int jg = j0 + g*8;
  long base = out_off + (((long)b*Cout + co)*2*Hin + 2*i)*Wout + 2*jg;
  #pragma unroll
  for(int p = 0; p < 8; p++){
    if(jg + p < Win){
      stm(out, base + 2*p,            fout, acc[p][0] + bv);
      stm(out, base + 2*p + 1,        fout, acc[p][1] + bv);
      stm(out, base + Wout + 2*p,     fout, acc[p][2] + bv);
      stm(out, base + Wout + 2*p + 1, fout, acc[p][3] + bv);
    }
  }
}

// ---------------- u4 special: Cout=2, thread-per-input-pixel ----------------
__global__ void k_convT4(const void* __restrict__ inA, int fA,
                         const void* __restrict__ inB, int fB,
                         const void* __restrict__ w, const void* __restrict__ bias,
                         void* __restrict__ out, long out_off, int fout_sel,
                         const int* __restrict__ dmode,
                         int Hin, int Win)
{
  __shared__ float sW[64*2*9];
  __shared__ float sB[2];
  int tid = threadIdx.x;
  int dm = *dmode;
  for(int e = tid; e < 64*2*9; e += 256) sW[e] = ldm(w, e, dm);
  if(tid < 2) sB[tid] = ldm(bias, tid, dm);
  __syncthreads();
  int i = blockIdx.x, b = blockIdx.z;
  int j = tid;
  if(j >= Win) return;
  float acc[2][4];
  #pragma unroll
  for(int co = 0; co < 2; co++){ acc[co][0]=0.f; acc[co][1]=0.f; acc[co][2]=0.f; acc[co][3]=0.f; }
  for(int ci = 0; ci < 64; ci++){
    const void* src = (ci < 32) ? inA : inB;
    int f = (ci < 32) ? fA : fB;
    int cc = ci & 31;
    long base = ((long)b*32 + cc)*Hin*Win + (long)i*Win + j;
    float a00 = ldm(src, base, f);
    float a01 = (j+1 < Win) ? ldm(src, base+1, f) : 0.f;
    float a10 = (i+1 < Hin) ? ldm(src, base+Win, f) : 0.f;
    float a11 = (i+1 < Hin && j+1 < Win) ? ldm(src, base+Win+1, f) : 0.f;
    #pragma unroll
    for(int co = 0; co < 2; co++){
      const float* wv = &sW[(ci*2 + co)*9];
      acc[co][0] += a00*wv[4];
      acc[co][1] += a00*wv[5] + a01*wv[3];
      acc[co][2] += a00*wv[7] + a10*wv[1];
      acc[co][3] += a00*wv[8] + a01*wv[6] + a10*wv[2] + a11*wv[0];
    }
  }
  int fout = (fout_sel == 2) ? dm : fout_sel;
  int Wout = 2*Win;
  #pragma unroll
  for(int co = 0; co < 2; co++){
    long base = out_off + (((long)b*2 + co)*2*Hin + 2*i)*Wout + 2*j;
    stm(out, base,          fout, acc[co][0] + sB[co]);
    stm(out, base + 1,      fout, acc[co][1] + sB[co]);
    stm(out, base + Wout,   fout, acc[co][2] + sB[co]);
    stm(out, base + Wout+1, fout, acc[co][3] + sB[co]);
  }
}

static inline int cdiv(long a, long b){ return (int)((a + b - 1) / b); }

extern "C" void kernel_launch(void* const* d_in, const int* in_sizes, int n_in,
                              void* d_out, int out_size, void* d_ws, size_t ws_size,
                              hipStream_t stream) {
  const void* x_in  = d_in[0];
  const int*  edges = (const int*)d_in[1];
  const int* src = edges;          // edges[0,:]
  const int* tgt = edges + 5000;   // edges[1,:]
  const void *w_d4=d_in[2],  *b_d4=d_in[3],  *a_d4=d_in[4];
  const void *w_d3=d_in[5],  *b_d3=d_in[6],  *a_d3=d_in[7];
  const void *w_d2=d_in[8],  *b_d2=d_in[9],  *a_d2=d_in[10];
  const void *w_d1=d_in[11], *b_d1=d_in[12], *a_d1=d_in[13];
  const void *w_bot=d_in[14],*b_bot=d_in[15],*a_bot=d_in[16];
  const void *wl1=d_in[17], *bl1=d_in[18], *wr1=d_in[19];
  const void *wl2=d_in[20], *bl2=d_in[21], *wr2=d_in[22];
  const void *w_u1=d_in[23], *b_u1=d_in[24], *a_u1=d_in[25];
  const void *w_u2=d_in[26], *b_u2=d_in[27], *a_u2=d_in[28];
  const void *w_u3=d_in[29], *b_u3=d_in[30], *a_u3=d_in[31];
  const void *w_u4=d_in[32], *b_u4=d_in[33];

  const int NNODE = 625, E = 5000, CG = 256;

  // tail: deg/mode (4KB) + 4 sage wT (1MB) + convT wT (u1 2.36MB, u2 0.59MB, u3 0.147MB)
  const long TAIL = 4096 + 4*262144L + (589824L + 147456L + 36864L) * 4;
  int Bc = 16;
  while(Bc > 1 && (7680000L * Bc + TAIL) > (long)ws_size) Bc >>= 1;

  char* wsb = (char*)d_ws;
  long o_xs1  = 2560000L * Bc;
  long o_BIGA = 3840000L * Bc;
  long o_BIGB = 6400000L * Bc;
  long o_deg  = 7680000L * Bc;
  bf16*  xs0 = (bf16*)wsb;                             // [d4 -> u4]
  bf16*  xs1 = (bf16*)(wsb + o_xs1);                   // [d3 -> u3]
  bf16*  xs2 = (bf16*)(wsb + o_BIGA);                  // [d2 -> u2]
  bf16*  xs3 = (bf16*)(wsb + o_BIGA +  640000L*Bc);    // [d1 -> u1]
  float* bot = (float*)(wsb + o_BIGA +  960000L*Bc);   // [bot -> u1] (=g2)
  float* xT  = (float*)(wsb + o_BIGA + 1600000L*Bc);   // [tr -> sage1]
  bf16*  u1  = (bf16*)(wsb + o_BIGA + 1600000L*Bc);    // alias xT (dead)
  bf16*  u3  = (bf16*)(wsb + o_BIGA);                  // alias BIGA (dead)
  float* agg = (float*)(wsb + o_BIGB);
  float* g1  = (float*)(wsb + o_BIGB +  640000L*Bc);   // [sage1 -> sage2]
  bf16*  u2  = (bf16*)(wsb + o_BIGB);                  // alias agg+g1 (dead)
  float* deg = (float*)(wsb + o_deg);                  // 625 fp32
  int*  mode = (int*)(wsb + o_deg + 3072);
  float* wlT1 = (float*)(wsb + o_deg + 4096);          // 4 x 65536 fp32
  float* wrT1 = wlT1 + 65536;
  float* wlT2 = wrT1 + 65536;
  float* wrT2 = wlT2 + 65536;
  float* wTu1 = wrT2 + 65536;                          // 512*128*9
  float* wTu2 = wTu1 + 589824;                         // 256*64*9
  float* wTu3 = wTu2 + 147456;                         // 128*32*9
  float* g2  = bot;

  hipLaunchKernelGGL(k_detect, dim3(1), dim3(1), 0, stream, w_d4, mode);

  hipMemsetAsync(deg, 0, NNODE*sizeof(float), stream);
  hipLaunchKernelGGL(k_deg, dim3(cdiv(E,256)), dim3(256), 0, stream, tgt, deg, E);
  hipLaunchKernelGGL(k_wtrans, dim3(256), dim3(256), 0, stream, wl1, wlT1, mode, CG);
  hipLaunchKernelGGL(k_wtrans, dim3(256), dim3(256), 0, stream, wr1, wrT1, mode, CG);
  hipLaunchKernelGGL(k_wtrans, dim3(256), dim3(256), 0, stream, wl2, wlT2, mode, CG);
  hipLaunchKernelGGL(k_wtrans, dim3(256), dim3(256), 0, stream, wr2, wrT2, mode, CG);
  hipLaunchKernelGGL(k_wtrans2, dim3(cdiv(589824,256)), dim3(256), 0, stream, w_u1, wTu1, mode, 512, 128);
  hipLaunchKernelGGL(k_wtrans2, dim3(cdiv(147456,256)), dim3(256), 0, stream, w_u2, wTu2, mode, 256, 64);
  hipLaunchKernelGGL(k_wtrans2, dim3(cdiv(36864,256)),  dim3(256), 0, stream, w_u3, wTu3, mode, 128, 32);

  for(int bo = 0; bo < 16; bo += Bc){
    long x_off   = (long)bo * 160000;
    long out_off = (long)bo * 320000;

    // ---- encoder ----
    { long n = (long)Bc*32*200*200;
      hipLaunchKernelGGL((k_conv3x3<2>), dim3(cdiv(n,256)), dim3(256), 0, stream,
                         x_in, x_off, 2, w_d4, b_d4, xs0, 0, mode, Bc, 1, 400, 400, 32, 200, 200);
      hipLaunchKernelGGL(k_inorm_prelu, dim3(Bc*32), dim3(256), 0, stream, xs0, 0, 40000, a_d4, mode); }
    { long n = (long)Bc*64*100*100;
      hipLaunchKernelGGL((k_conv3x3<2>), dim3(cdiv(n,256)), dim3(256), 0, stream,
                         xs0, 0, 0, w_d3, b_d3, xs1, 0, mode, Bc, 32, 200, 200, 64, 100, 100);
      hipLaunchKernelGGL(k_inorm_prelu, dim3(Bc*64), dim3(256), 0, stream, xs1, 0, 10000, a_d3, mode); }
    { long n = (long)Bc*128*50*50;
      hipLaunchKernelGGL((k_conv3x3<2>), dim3(cdiv(n,256)), dim3(256), 0, stream,
                         xs1, 0, 0, w_d2, b_d2, xs2, 0, mode, Bc, 64, 100, 100, 128, 50, 50);
      hipLaunchKernelGGL(k_inorm_prelu, dim3(Bc*128), dim3(256), 0, stream, xs2, 0, 2500, a_d2, mode); }
    { long n = (long)Bc*256*25*25;
      hipLaunchKernelGGL((k_conv3x3<2>), dim3(cdiv(n,256)), dim3(256), 0, stream,
                         xs2, 0, 0, w_d1, b_d1, xs3, 0, mode, Bc, 128, 50, 50, 256, 25, 25);
      hipLaunchKernelGGL(k_inorm_prelu, dim3(Bc*256), dim3(256), 0, stream, xs3, 0, 625, a_d1, mode); }
    { long n = (long)Bc*256*25*25;
      hipLaunchKernelGGL((k_conv3x3<1>), dim3(cdiv(n,256)), dim3(256), 0, stream,
                         xs3, 0, 0, w_bot, b_bot, bot, 1, mode, Bc, 256, 25, 25, 256, 25, 25);
      hipLaunchKernelGGL(k_inorm_prelu, dim3(Bc*256), dim3(256), 0, stream, bot, 1, 625, a_bot, mode); }

    // ---- GNN ----
    { long n = (long)Bc*CG*NNODE;
      hipLaunchKernelGGL(k_transpose, dim3(cdiv(n,256)), dim3(256), 0, stream, bot, xT, Bc, CG, NNODE); }
    hipMemsetAsync(agg, 0, 640000L*Bc, stream);
    hipLaunchKernelGGL(k_scatter, dim3(cdiv((long)E*CG,256)), dim3(256), 0, stream, xT, src, tgt, agg, E, CG, NNODE, Bc);
    hipLaunchKernelGGL(k_sage2, dim3(125, Bc), dim3(256), 0, stream,
                       xT, agg, deg, wlT1, wrT1, bl1, g1, mode, Bc, NNODE, CG, 0);
    hipMemsetAsync(agg, 0, 640000L*Bc, stream);
    hipLaunchKernelGGL(k_scatter, dim3(cdiv((long)E*CG,256)), dim3(256), 0, stream, g1, src, tgt, agg, E, CG, NNODE, Bc);
    hipLaunchKernelGGL(k_sage2, dim3(125, Bc), dim3(256), 0, stream,
                       g1, agg, deg, wlT2, wrT2, bl2, g2, mode, Bc, NNODE, CG, 1);

    // ---- decoder (row-GEMM convT) ----
    // u1: 25x25, Cin 512 (xs3 bf16 + g2 fp32) -> 128 @ 50x50; CTO=128,G=2 span16, ntj=2
    hipLaunchKernelGGL((k_convT3<128,2,8>), dim3(25*2, 1, Bc), dim3(256), 0, stream,
                       xs3, 0, 256, g2, 1, 256, wTu1, b_u1, u1, 0L, 0, mode, 25, 25, 2);
    hipLaunchKernelGGL(k_inorm_prelu, dim3(Bc*128), dim3(256), 0, stream, u1, 0, 2500, a_u1, mode);
    // u2: 50x50, Cin 256 -> 64 @ 100x100; CTO=64,G=4 span32, ntj=2
    hipLaunchKernelGGL((k_convT3<64,4,8>), dim3(50*2, 1, Bc), dim3(256), 0, stream,
                       xs2, 0, 128, u1, 0, 128, wTu2, b_u2, u2, 0L, 0, mode, 50, 50, 2);
    hipLaunchKernelGGL(k_inorm_prelu, dim3(Bc*64), dim3(256), 0, stream, u2, 0, 10000, a_u2, mode);
    // u3: 100x100, Cin 128 -> 32 @ 200x200; CTO=32,G=8 span64, ntj=2
    hipLaunchKernelGGL((k_convT3<32,8,8>), dim3(100*2, 1, Bc), dim3(256), 0, stream,
                       xs1, 0, 64, u2, 0, 64, wTu3, b_u3, u3, 0L, 0, mode, 100, 100, 2);
    hipLaunchKernelGGL(k_inorm_prelu, dim3(Bc*32), dim3(256), 0, stream, u3, 0, 40000, a_u3, mode);
    // u4: 200x200, Cin 64 -> 2 @ 400x400; thread-per-input-pixel
    hipLaunchKernelGGL(k_convT4, dim3(200, 1, Bc), dim3(256), 0, stream,
                       xs0, 0, u3, 0, w_u4, b_u4, d_out, out_off, 2, mode, 200, 200);
  }
}

// Round 9
// 13932.347 us; speedup vs baseline: 1.9614x; 1.9614x over previous
//
#include <hip/hip_runtime.h>
#include <hip/hip_bf16.h>

typedef __hip_bfloat16 bf16;

static __device__ __forceinline__ float bf(const bf16 v){ return __bfloat162float(v); }

// flag f: 0 = bf16, 1 = fp32
static __device__ __forceinline__ float ldm(const void* p, long i, int f){
  return f ? ((const float*)p)[i] : __bfloat162float(((const bf16*)p)[i]);
}
static __device__ __forceinline__ void stm(void* p, long i, int f, float v){
  if(f) ((float*)p)[i] = v; else ((bf16*)p)[i] = __float2bfloat16(v);
}

// ---------------- input dtype detector (bit-level correct) ----------------
// bf16 == top 16 bits of fp32: test LOW 16 bits of each word as bf16.
__global__ void k_detect(const void* __restrict__ w, int* __restrict__ mode){
  if(blockIdx.x == 0 && threadIdx.x == 0){
    const unsigned int* u = (const unsigned int*)w;
    int saneLo = 0;
    for(int i = 0; i < 64; i++){
      unsigned short lo = (unsigned short)(u[i] & 0xFFFFu);
      unsigned int fw = ((unsigned int)lo) << 16;
      float v; __builtin_memcpy(&v, &fw, 4);
      float a = fabsf(v);
      if(a > 1e-7f && a < 100.f) saneLo++;
    }
    *mode = (saneLo >= 48) ? 0 : 1;   // 0 = bf16, 1 = fp32
  }
}

// ---------------- SAGE weight transpose: wT[c][o] = w[o][c], fp32 out ----------------
__global__ void k_wtrans(const void* __restrict__ w, float* __restrict__ wT,
                         const int* __restrict__ dmode, int C){
  int idx = blockIdx.x * 256 + threadIdx.x;
  if(idx >= C * C) return;
  int dm = *dmode;
  int o = idx % C, c = idx / C;
  wT[idx] = ldm(w, (long)o * C + c, dm);
}

// ---------------- convT weight transpose: wT[(ci*9+k)*Cout+co] = w[(ci*Cout+co)*9+k], bf16 out ----------------
__global__ void k_wtrans2(const void* __restrict__ w, bf16* __restrict__ wT,
                          const int* __restrict__ dmode, int Cin, int Cout){
  int idx = blockIdx.x * 256 + threadIdx.x;
  if(idx >= Cin * Cout * 9) return;
  int dm = *dmode;
  int co = idx % Cout; int t = idx / Cout; int k = t % 9; int ci = t / 9;
  wT[idx] = __float2bfloat16(ldm(w, ((long)ci * Cout + co) * 9 + k, dm));
}

// ---------------- direct conv 3x3, pad 1, stride S ----------------
template<int S>
__global__ void k_conv3x3(const void* __restrict__ in, long in_off, int fin_sel,
                          const void* __restrict__ w, const void* __restrict__ bias,
                          void* __restrict__ out, int fout,
                          const int* __restrict__ dmode,
                          int B, int Cin, int Hin, int Win, int Cout, int Hout, int Wout)
{
  long idx = (long)blockIdx.x * 256 + threadIdx.x;
  long total = (long)B * Cout * Hout * Wout;
  if(idx >= total) return;
  int dm = *dmode;
  int fin = (fin_sel == 2) ? dm : fin_sel;
  int wo = (int)(idx % Wout); long t = idx / Wout;
  int ho = (int)(t % Hout);   t /= Hout;
  int co = (int)(t % Cout);   int b = (int)(t / Cout);
  float acc = ldm(bias, co, dm);
  int hbase = ho * S - 1, wbase = wo * S - 1;
  long wbi = (long)co * Cin * 9;
  long ibase = in_off + (long)b * Cin * Hin * Win;
  for(int ci = 0; ci < Cin; ci++){
    long ip = ibase + (long)ci * Hin * Win;
    long wp = wbi + (long)ci * 9;
    #pragma unroll
    for(int kh = 0; kh < 3; kh++){
      int hi = hbase + kh;
      if((unsigned)hi >= (unsigned)Hin) continue;
      long rp = ip + (long)hi * Win;
      #pragma unroll
      for(int kw = 0; kw < 3; kw++){
        int wi = wbase + kw;
        if((unsigned)wi >= (unsigned)Win) continue;
        acc += ldm(in, rp + wi, fin) * ldm(w, wp + kh*3 + kw, dm);
      }
    }
  }
  stm(out, idx, fout, acc);
}

// ---------------- InstanceNorm (affine=False) + PReLU, in place ----------------
__global__ void k_inorm_prelu(void* __restrict__ x, int f, int HW,
                              const void* __restrict__ a, const int* __restrict__ dmode)
{
  int dm = *dmode;
  long base = (long)blockIdx.x * HW;
  float s = 0.f, s2 = 0.f;
  for(int i = threadIdx.x; i < HW; i += 256){ float v = ldm(x, base + i, f); s += v; s2 += v*v; }
  __shared__ float sh[256], sh2[256];
  sh[threadIdx.x] = s; sh2[threadIdx.x] = s2; __syncthreads();
  for(int off = 128; off > 0; off >>= 1){
    if(threadIdx.x < off){ sh[threadIdx.x] += sh[threadIdx.x+off]; sh2[threadIdx.x] += sh2[threadIdx.x+off]; }
    __syncthreads();
  }
  float mean = sh[0] / HW;
  float var  = sh2[0] / HW - mean * mean;
  float inv  = rsqrtf(fmaxf(var, 0.f) + 1e-5f);
  float alpha = ldm(a, 0, dm);
  for(int i = threadIdx.x; i < HW; i += 256){
    float v = (ldm(x, base + i, f) - mean) * inv;
    stm(x, base + i, f, v >= 0.f ? v : alpha * v);
  }
}

// ---------------- transpose [B,C,N] -> [B,N,C] (fp32) ----------------
__global__ void k_transpose(const float* __restrict__ in, float* __restrict__ out, int B, int C, int N){
  long idx = (long)blockIdx.x * 256 + threadIdx.x;
  long total = (long)B * C * N; if(idx >= total) return;
  int c = (int)(idx % C); long t = idx / C; int n = (int)(t % N); int b = (int)(t / N);
  out[idx] = in[((long)b * C + c) * N + n];
}

// ---------------- degree ----------------
__global__ void k_deg(const int* __restrict__ tgt, float* __restrict__ deg, int E){
  int e = blockIdx.x * 256 + threadIdx.x;
  if(e < E) atomicAdd(&deg[tgt[e]], 1.0f);
}

// ---------------- scatter add: agg[b,tgt,c] += x[b,src,c]  ([B,N,C] fp32) ----------------
__global__ void k_scatter(const float* __restrict__ xT, const int* __restrict__ src,
                          const int* __restrict__ tgt, float* __restrict__ agg,
                          int E, int C, int N, int B)
{
  int t = blockIdx.x * 256 + threadIdx.x;
  if(t >= E * C) return;
  int c = t % C; int e = t / C;
  int s = src[e], d = tgt[e];
  for(int b = 0; b < B; b++){
    atomicAdd(&agg[((long)b * N + d) * C + c], xT[((long)b * N + s) * C + c]);
  }
}

// ---------------- SAGE as tiled GEMM ----------------
#define TN 5
__global__ void k_sage2(const float* __restrict__ xT, const float* __restrict__ agg,
                        const float* __restrict__ deg,
                        const float* __restrict__ wlT, const float* __restrict__ wrT,
                        const void* __restrict__ bl,
                        float* __restrict__ out, const int* __restrict__ dmode,
                        int B, int N, int C, int transpose_out)
{
  int o  = threadIdx.x;
  int n0 = blockIdx.x * TN;
  int b  = blockIdx.y;
  __shared__ float sX[TN][256];
  __shared__ float sA[TN][256];
  #pragma unroll
  for(int j = 0; j < TN; j++){
    int n = n0 + j;
    float dinv = 1.0f / fmaxf(deg[n], 1.0f);
    long base = ((long)b * N + n) * C;
    sX[j][o] = xT[base + o];
    sA[j][o] = agg[base + o] * dinv;
  }
  __syncthreads();
  int dm = *dmode;
  float bv = ldm(bl, o, dm);
  float acc[TN];
  #pragma unroll
  for(int j = 0; j < TN; j++) acc[j] = bv;
  #pragma unroll 4
  for(int c = 0; c < 256; c++){
    float wlv = wlT[(long)c * 256 + o];
    float wrv = wrT[(long)c * 256 + o];
    #pragma unroll
    for(int j = 0; j < TN; j++){
      acc[j] += sA[j][c] * wlv + sX[j][c] * wrv;
    }
  }
  #pragma unroll
  for(int j = 0; j < TN; j++){
    int n = n0 + j;
    float v = fmaxf(acc[j], 0.f);
    if(transpose_out) out[((long)b * C + o) * N + n] = v;
    else              out[((long)b * N + n) * C + o] = v;
  }
}

// ---------------- ConvTranspose2d k=3 s=2 p=1 op=1 — full-width tiles ----------------
// One block = 32-co tile x FULL image width x ROWS input rows. This bounds
// total weight traffic at slice_bytes x (Hin/ROWS) x (Cout/32) x B blocks
// (vs whole-table x 800 blocks before: 1.9GB -> ~100MB). Thread = (co, g);
// thread owns cols [g*SEG, g*SEG+SEG) of all ROWS rows. Inputs staged
// full-width (zero-padded) per CC-channel chunk.
// Parity quad: out[2i][2j]=a00*w4; out[2i][2j+1]=a00*w5+a01*w3;
// out[2i+1][2j]=a00*w7+a10*w1; out[2i+1][2j+1]=a00*w8+a01*w6+a10*w2+a11*w0.
template<int COT, int ROWS, int SEG, int CC>
__global__ void k_convT5(const void* __restrict__ inA, int fA, int C1,
                         const void* __restrict__ inB, int fB, int C2,
                         const bf16* __restrict__ wT, const void* __restrict__ bias,
                         void* __restrict__ out, int fout,
                         const int* __restrict__ dmode,
                         int Hin, int Win, int Cout)
{
  constexpr int NG = 256 / COT;
  constexpr int PC = NG * SEG + 1;
  __shared__ float sX[CC][ROWS+1][PC];
  int tid = threadIdx.x;
  int co = tid % COT;
  int g  = tid / COT;
  int i0 = blockIdx.x * ROWS;
  int co0 = blockIdx.y * COT;
  int b  = blockIdx.z;
  int dm = *dmode;
  int Cin = C1 + C2;
  int Wout = 2 * Win;

  float acc[ROWS][SEG][4];
  #pragma unroll
  for(int r = 0; r < ROWS; r++)
    #pragma unroll
    for(int p = 0; p < SEG; p++){
      acc[r][p][0]=0.f; acc[r][p][1]=0.f; acc[r][p][2]=0.f; acc[r][p][3]=0.f;
    }

  for(int ci0 = 0; ci0 < Cin; ci0 += CC){
    for(int e = tid; e < CC*(ROWS+1)*PC; e += 256){
      int s = e / ((ROWS+1)*PC); int rem = e % ((ROWS+1)*PC);
      int r = rem / PC, c = rem % PC;
      int ci = ci0 + s;
      int ii = i0 + r;
      float v = 0.f;
      if(ii < Hin && c < Win){
        v = (ci < C1) ? ldm(inA, ((long)b*C1 + ci)*Hin*Win + (long)ii*Win + c, fA)
                      : ldm(inB, ((long)b*C2 + (ci-C1))*Hin*Win + (long)ii*Win + c, fB);
      }
      sX[s][r][c] = v;
    }
    __syncthreads();
    for(int s = 0; s < CC; s++){
      int ci = ci0 + s;
      float wv[9];
      #pragma unroll
      for(int k = 0; k < 9; k++) wv[k] = bf(wT[((long)ci*9 + k)*Cout + co0 + co]);
      #pragma unroll
      for(int r = 0; r < ROWS; r++){
        float x0[SEG+1], x1[SEG+1];
        #pragma unroll
        for(int c = 0; c <= SEG; c++){
          x0[c] = sX[s][r][g*SEG + c];
          x1[c] = sX[s][r+1][g*SEG + c];
        }
        #pragma unroll
        for(int p = 0; p < SEG; p++){
          float a00 = x0[p], a01 = x0[p+1], a10 = x1[p], a11 = x1[p+1];
          acc[r][p][0] += a00*wv[4];
          acc[r][p][1] += a00*wv[5] + a01*wv[3];
          acc[r][p][2] += a00*wv[7] + a10*wv[1];
          acc[r][p][3] += a00*wv[8] + a01*wv[6] + a10*wv[2] + a11*wv[0];
        }
      }
    }
    __syncthreads();
  }

  float bv = ldm(bias, co0 + co, dm);
  #pragma unroll
  for(int r = 0; r < ROWS; r++){
    int i = i0 + r;
    if(i >= Hin) continue;
    #pragma unroll
    for(int p = 0; p < SEG; p++){
      int j = g*SEG + p;
      if(j >= Win) continue;
      long base = (((long)b*Cout + co0 + co)*2*Hin + 2*i)*Wout + 2*j;
      stm(out, base,            fout, acc[r][p][0] + bv);
      stm(out, base + 1,        fout, acc[r][p][1] + bv);
      stm(out, base + Wout,     fout, acc[r][p][2] + bv);
      stm(out, base + Wout + 1, fout, acc[r][p][3] + bv);
    }
  }
}

// ---------------- u4 special: Cout=2, thread-per-input-pixel ----------------
__global__ void k_convT4(const void* __restrict__ inA, int fA,
                         const void* __restrict__ inB, int fB,
                         const void* __restrict__ w, const void* __restrict__ bias,
                         void* __restrict__ out, long out_off, int fout_sel,
                         const int* __restrict__ dmode,
                         int Hin, int Win)
{
  __shared__ float sW[64*2*9];
  __shared__ float sB[2];
  int tid = threadIdx.x;
  int dm = *dmode;
  for(int e = tid; e < 64*2*9; e += 256) sW[e] = ldm(w, e, dm);
  if(tid < 2) sB[tid] = ldm(bias, tid, dm);
  __syncthreads();
  int i = blockIdx.x, b = blockIdx.z;
  int j = tid;
  if(j >= Win) return;
  float acc[2][4];
  #pragma unroll
  for(int co = 0; co < 2; co++){ acc[co][0]=0.f; acc[co][1]=0.f; acc[co][2]=0.f; acc[co][3]=0.f; }
  for(int ci = 0; ci < 64; ci++){
    const void* src = (ci < 32) ? inA : inB;
    int f = (ci < 32) ? fA : fB;
    int cc = ci & 31;
    long base = ((long)b*32 + cc)*Hin*Win + (long)i*Win + j;
    float a00 = ldm(src, base, f);
    float a01 = (j+1 < Win) ? ldm(src, base+1, f) : 0.f;
    float a10 = (i+1 < Hin) ? ldm(src, base+Win, f) : 0.f;
    float a11 = (i+1 < Hin && j+1 < Win) ? ldm(src, base+Win+1, f) : 0.f;
    #pragma unroll
    for(int co = 0; co < 2; co++){
      const float* wv = &sW[(ci*2 + co)*9];
      acc[co][0] += a00*wv[4];
      acc[co][1] += a00*wv[5] + a01*wv[3];
      acc[co][2] += a00*wv[7] + a10*wv[1];
      acc[co][3] += a00*wv[8] + a01*wv[6] + a10*wv[2] + a11*wv[0];
    }
  }
  int fout = (fout_sel == 2) ? dm : fout_sel;
  int Wout = 2*Win;
  #pragma unroll
  for(int co = 0; co < 2; co++){
    long base = out_off + (((long)b*2 + co)*2*Hin + 2*i)*Wout + 2*j;
    stm(out, base,          fout, acc[co][0] + sB[co]);
    stm(out, base + 1,      fout, acc[co][1] + sB[co]);
    stm(out, base + Wout,   fout, acc[co][2] + sB[co]);
    stm(out, base + Wout+1, fout, acc[co][3] + sB[co]);
  }
}

static inline int cdiv(long a, long b){ return (int)((a + b - 1) / b); }

extern "C" void kernel_launch(void* const* d_in, const int* in_sizes, int n_in,
                              void* d_out, int out_size, void* d_ws, size_t ws_size,
                              hipStream_t stream) {
  const void* x_in  = d_in[0];
  const int*  edges = (const int*)d_in[1];
  const int* src = edges;          // edges[0,:]
  const int* tgt = edges + 5000;   // edges[1,:]
  const void *w_d4=d_in[2],  *b_d4=d_in[3],  *a_d4=d_in[4];
  const void *w_d3=d_in[5],  *b_d3=d_in[6],  *a_d3=d_in[7];
  const void *w_d2=d_in[8],  *b_d2=d_in[9],  *a_d2=d_in[10];
  const void *w_d1=d_in[11], *b_d1=d_in[12], *a_d1=d_in[13];
  const void *w_bot=d_in[14],*b_bot=d_in[15],*a_bot=d_in[16];
  const void *wl1=d_in[17], *bl1=d_in[18], *wr1=d_in[19];
  const void *wl2=d_in[20], *bl2=d_in[21], *wr2=d_in[22];
  const void *w_u1=d_in[23], *b_u1=d_in[24], *a_u1=d_in[25];
  const void *w_u2=d_in[26], *b_u2=d_in[27], *a_u2=d_in[28];
  const void *w_u3=d_in[29], *b_u3=d_in[30], *a_u3=d_in[31];
  const void *w_u4=d_in[32], *b_u4=d_in[33];

  const int NNODE = 625, E = 5000, CG = 256;

  // tail: deg/mode (4KB) + 4 sage wT fp32 (1MB) + convT wT bf16 (1.55MB)
  const long TAIL = 4096 + 4*262144L + (589824L + 147456L + 36864L) * 2;
  int Bc = 16;
  while(Bc > 1 && (7680000L * Bc + TAIL) > (long)ws_size) Bc >>= 1;

  char* wsb = (char*)d_ws;
  long o_xs1  = 2560000L * Bc;
  long o_BIGA = 3840000L * Bc;
  long o_BIGB = 6400000L * Bc;
  long o_deg  = 7680000L * Bc;
  bf16*  xs0 = (bf16*)wsb;                             // [d4 -> u4]
  bf16*  xs1 = (bf16*)(wsb + o_xs1);                   // [d3 -> u3]
  bf16*  xs2 = (bf16*)(wsb + o_BIGA);                  // [d2 -> u2]
  bf16*  xs3 = (bf16*)(wsb + o_BIGA +  640000L*Bc);    // [d1 -> u1]
  float* bot = (float*)(wsb + o_BIGA +  960000L*Bc);   // [bot -> u1] (=g2)
  float* xT  = (float*)(wsb + o_BIGA + 1600000L*Bc);   // [tr -> sage1]
  bf16*  u1  = (bf16*)(wsb + o_BIGA + 1600000L*Bc);    // alias xT (dead)
  bf16*  u3  = (bf16*)(wsb + o_BIGA);                  // alias BIGA (dead)
  float* agg = (float*)(wsb + o_BIGB);
  float* g1  = (float*)(wsb + o_BIGB +  640000L*Bc);   // [sage1 -> sage2]
  bf16*  u2  = (bf16*)(wsb + o_BIGB);                  // alias agg+g1 (dead)
  float* deg = (float*)(wsb + o_deg);                  // 625 fp32
  int*  mode = (int*)(wsb + o_deg + 3072);
  float* wlT1 = (float*)(wsb + o_deg + 4096);          // 4 x 65536 fp32
  float* wrT1 = wlT1 + 65536;
  float* wlT2 = wrT1 + 65536;
  float* wrT2 = wlT2 + 65536;
  bf16*  wTu1 = (bf16*)(wrT2 + 65536);                 // 512*128*9 bf16
  bf16*  wTu2 = wTu1 + 589824;                         // 256*64*9
  bf16*  wTu3 = wTu2 + 147456;                         // 128*32*9
  float* g2  = bot;

  hipLaunchKernelGGL(k_detect, dim3(1), dim3(1), 0, stream, w_d4, mode);

  hipMemsetAsync(deg, 0, NNODE*sizeof(float), stream);
  hipLaunchKernelGGL(k_deg, dim3(cdiv(E,256)), dim3(256), 0, stream, tgt, deg, E);
  hipLaunchKernelGGL(k_wtrans, dim3(256), dim3(256), 0, stream, wl1, wlT1, mode, CG);
  hipLaunchKernelGGL(k_wtrans, dim3(256), dim3(256), 0, stream, wr1, wrT1, mode, CG);
  hipLaunchKernelGGL(k_wtrans, dim3(256), dim3(256), 0, stream, wl2, wlT2, mode, CG);
  hipLaunchKernelGGL(k_wtrans, dim3(256), dim3(256), 0, stream, wr2, wrT2, mode, CG);
  hipLaunchKernelGGL(k_wtrans2, dim3(cdiv(589824,256)), dim3(256), 0, stream, w_u1, wTu1, mode, 512, 128);
  hipLaunchKernelGGL(k_wtrans2, dim3(cdiv(147456,256)), dim3(256), 0, stream, w_u2, wTu2, mode, 256, 64);
  hipLaunchKernelGGL(k_wtrans2, dim3(cdiv(36864,256)),  dim3(256), 0, stream, w_u3, wTu3, mode, 128, 32);

  for(int bo = 0; bo < 16; bo += Bc){
    long x_off   = (long)bo * 160000;
    long out_off = (long)bo * 320000;

    // ---- encoder ----
    { long n = (long)Bc*32*200*200;
      hipLaunchKernelGGL((k_conv3x3<2>), dim3(cdiv(n,256)), dim3(256), 0, stream,
                         x_in, x_off, 2, w_d4, b_d4, xs0, 0, mode, Bc, 1, 400, 400, 32, 200, 200);
      hipLaunchKernelGGL(k_inorm_prelu, dim3(Bc*32), dim3(256), 0, stream, xs0, 0, 40000, a_d4, mode); }
    { long n = (long)Bc*64*100*100;
      hipLaunchKernelGGL((k_conv3x3<2>), dim3(cdiv(n,256)), dim3(256), 0, stream,
                         xs0, 0, 0, w_d3, b_d3, xs1, 0, mode, Bc, 32, 200, 200, 64, 100, 100);
      hipLaunchKernelGGL(k_inorm_prelu, dim3(Bc*64), dim3(256), 0, stream, xs1, 0, 10000, a_d3, mode); }
    { long n = (long)Bc*128*50*50;
      hipLaunchKernelGGL((k_conv3x3<2>), dim3(cdiv(n,256)), dim3(256), 0, stream,
                         xs1, 0, 0, w_d2, b_d2, xs2, 0, mode, Bc, 64, 100, 100, 128, 50, 50);
      hipLaunchKernelGGL(k_inorm_prelu, dim3(Bc*128), dim3(256), 0, stream, xs2, 0, 2500, a_d2, mode); }
    { long n = (long)Bc*256*25*25;
      hipLaunchKernelGGL((k_conv3x3<2>), dim3(cdiv(n,256)), dim3(256), 0, stream,
                         xs2, 0, 0, w_d1, b_d1, xs3, 0, mode, Bc, 128, 50, 50, 256, 25, 25);
      hipLaunchKernelGGL(k_inorm_prelu, dim3(Bc*256), dim3(256), 0, stream, xs3, 0, 625, a_d1, mode); }
    { long n = (long)Bc*256*25*25;
      hipLaunchKernelGGL((k_conv3x3<1>), dim3(cdiv(n,256)), dim3(256), 0, stream,
                         xs3, 0, 0, w_bot, b_bot, bot, 1, mode, Bc, 256, 25, 25, 256, 25, 25);
      hipLaunchKernelGGL(k_inorm_prelu, dim3(Bc*256), dim3(256), 0, stream, bot, 1, 625, a_bot, mode); }

    // ---- GNN ----
    { long n = (long)Bc*CG*NNODE;
      hipLaunchKernelGGL(k_transpose, dim3(cdiv(n,256)), dim3(256), 0, stream, bot, xT, Bc, CG, NNODE); }
    hipMemsetAsync(agg, 0, 640000L*Bc, stream);
    hipLaunchKernelGGL(k_scatter, dim3(cdiv((long)E*CG,256)), dim3(256), 0, stream, xT, src, tgt, agg, E, CG, NNODE, Bc);
    hipLaunchKernelGGL(k_sage2, dim3(125, Bc), dim3(256), 0, stream,
                       xT, agg, deg, wlT1, wrT1, bl1, g1, mode, Bc, NNODE, CG, 0);
    hipMemsetAsync(agg, 0, 640000L*Bc, stream);
    hipLaunchKernelGGL(k_scatter, dim3(cdiv((long)E*CG,256)), dim3(256), 0, stream, g1, src, tgt, agg, E, CG, NNODE, Bc);
    hipLaunchKernelGGL(k_sage2, dim3(125, Bc), dim3(256), 0, stream,
                       g1, agg, deg, wlT2, wrT2, bl2, g2, mode, Bc, NNODE, CG, 1);

    // ---- decoder (full-width-tile convT) ----
    // u1: 25x25, Cin 512 (xs3 bf16 + g2 fp32) -> 128 @ 50x50; ROWS=5, SEG=4, 4 co-tiles
    hipLaunchKernelGGL((k_convT5<32,5,4,8>), dim3(5, 4, Bc), dim3(256), 0, stream,
                       xs3, 0, 256, g2, 1, 256, wTu1, b_u1, u1, 0, mode, 25, 25, 128);
    hipLaunchKernelGGL(k_inorm_prelu, dim3(Bc*128), dim3(256), 0, stream, u1, 0, 2500, a_u1, mode);
    // u2: 50x50, Cin 256 -> 64 @ 100x100; ROWS=2, SEG=7, 2 co-tiles
    hipLaunchKernelGGL((k_convT5<32,2,7,8>), dim3(25, 2, Bc), dim3(256), 0, stream,
                       xs2, 0, 128, u1, 0, 128, wTu2, b_u2, u2, 0, mode, 50, 50, 64);
    hipLaunchKernelGGL(k_inorm_prelu, dim3(Bc*64), dim3(256), 0, stream, u2, 0, 10000, a_u2, mode);
    // u3: 100x100, Cin 128 -> 32 @ 200x200; ROWS=1, SEG=13, 1 co-tile
    hipLaunchKernelGGL((k_convT5<32,1,13,8>), dim3(100, 1, Bc), dim3(256), 0, stream,
                       xs1, 0, 64, u2, 0, 64, wTu3, b_u3, u3, 0, mode, 100, 100, 32);
    hipLaunchKernelGGL(k_inorm_prelu, dim3(Bc*32), dim3(256), 0, stream, u3, 0, 40000, a_u3, mode);
    // u4: 200x200, Cin 64 -> 2 @ 400x400
    hipLaunchKernelGGL(k_convT4, dim3(200, 1, Bc), dim3(256), 0, stream,
                       xs0, 0, u3, 0, w_u4, b_u4, d_out, out_off, 2, mode, 200, 200);
  }
}

// Round 11
// 4163.995 us; speedup vs baseline: 6.5627x; 3.3459x over previous
//
#include <hip/hip_runtime.h>
#include <hip/hip_bf16.h>

typedef __hip_bfloat16 bf16;

static __device__ __forceinline__ float bf(const bf16 v){ return __bfloat162float(v); }

// flag f: 0 = bf16, 1 = fp32
static __device__ __forceinline__ float ldm(const void* p, long i, int f){
  return f ? ((const float*)p)[i] : __bfloat162float(((const bf16*)p)[i]);
}
static __device__ __forceinline__ void stm(void* p, long i, int f, float v){
  if(f) ((float*)p)[i] = v; else ((bf16*)p)[i] = __float2bfloat16(v);
}

// ---------------- input dtype detector (bit-level correct) ----------------
__global__ void k_detect(const void* __restrict__ w, int* __restrict__ mode){
  if(blockIdx.x == 0 && threadIdx.x == 0){
    const unsigned int* u = (const unsigned int*)w;
    int saneLo = 0;
    for(int i = 0; i < 64; i++){
      unsigned short lo = (unsigned short)(u[i] & 0xFFFFu);
      unsigned int fw = ((unsigned int)lo) << 16;
      float v; __builtin_memcpy(&v, &fw, 4);
      float a = fabsf(v);
      if(a > 1e-7f && a < 100.f) saneLo++;
    }
    *mode = (saneLo >= 48) ? 0 : 1;   // 0 = bf16, 1 = fp32
  }
}

// ---------------- SAGE weight transpose: wT[c][o] = w[o][c], fp32 out ----------------
__global__ void k_wtrans(const void* __restrict__ w, float* __restrict__ wT,
                         const int* __restrict__ dmode, int C){
  int idx = blockIdx.x * 256 + threadIdx.x;
  if(idx >= C * C) return;
  int dm = *dmode;
  int o = idx % C, c = idx / C;
  wT[idx] = ldm(w, (long)o * C + c, dm);
}

// ---------------- convT weight transpose: [Cin,Cout,3,3] -> wT[(ci*9+k)*Cout+co], bf16 ----------------
__global__ void k_wtrans2(const void* __restrict__ w, bf16* __restrict__ wT,
                          const int* __restrict__ dmode, int Cin, int Cout){
  int idx = blockIdx.x * 256 + threadIdx.x;
  if(idx >= Cin * Cout * 9) return;
  int dm = *dmode;
  int co = idx % Cout; int t = idx / Cout; int k = t % 9; int ci = t / 9;
  wT[idx] = __float2bfloat16(ldm(w, ((long)ci * Cout + co) * 9 + k, dm));
}

// ---------------- conv weight transpose: [Cout,Cin,3,3] -> wT[(ci*9+k)*Cout+co], bf16 ----------------
__global__ void k_wtrans3(const void* __restrict__ w, bf16* __restrict__ wT,
                          const int* __restrict__ dmode, int Cin, int Cout){
  int idx = blockIdx.x * 256 + threadIdx.x;
  if(idx >= Cin * Cout * 9) return;
  int dm = *dmode;
  int co = idx % Cout; int t = idx / Cout; int k = t % 9; int ci = t / 9;
  wT[idx] = __float2bfloat16(ldm(w, ((long)co * Cin + ci) * 9 + k, dm));
}

// ---------------- conv 3x3 — full-width row tiles, LDS-staged ----------------
// Block = COT co-lanes x (one output row x full width). Thread (co,g) owns
// SEG consecutive out cols (NG*SEG == Wout). Inputs: 3 rows x full padded
// width staged per CC-channel chunk. Weights pre-transposed: lane-coalesced.
template<int COT, int SEG, int CC, int S, int WIP>
__global__ __launch_bounds__(256, 2)
void k_conv6(const void* __restrict__ in, long in_off, int fin_sel,
             const bf16* __restrict__ wT, const void* __restrict__ bias,
             void* __restrict__ out, int fout,
             const int* __restrict__ dmode,
             int Cin, int Hin, int Win, int Cout, int Hout, int Wout)
{
  constexpr int NG = 256 / COT;
  __shared__ float sX[CC][3][WIP];
  int tid = threadIdx.x;
  int co = tid % COT;
  int g  = tid / COT;
  int ho = blockIdx.x;
  int co0 = blockIdx.y * COT;
  int b  = blockIdx.z;
  int dm = *dmode;
  int fin = (fin_sel == 2) ? dm : fin_sel;

  float acc[SEG];
  #pragma unroll
  for(int p = 0; p < SEG; p++) acc[p] = 0.f;

  for(int ci0 = 0; ci0 < Cin; ci0 += CC){
    for(int e = tid; e < CC*3*WIP; e += 256){
      int s = e / (3*WIP); int rem = e % (3*WIP);
      int r = rem / WIP, c = rem % WIP;
      int ci = ci0 + s;
      int ir = S*ho - 1 + r;
      int ic = c - 1;
      float v = 0.f;
      if(ir >= 0 && ir < Hin && ic >= 0 && ic < Win)
        v = ldm(in, in_off + ((long)b*Cin + ci)*Hin*Win + (long)ir*Win + ic, fin);
      sX[s][r][c] = v;
    }
    __syncthreads();
    for(int s = 0; s < CC; s++){
      int ci = ci0 + s;
      float wv[9];
      #pragma unroll
      for(int k = 0; k < 9; k++) wv[k] = bf(wT[((long)ci*9 + k)*Cout + co0 + co]);
      #pragma unroll
      for(int p = 0; p < SEG; p++){
        int j = g*SEG + p;
        float a = acc[p];
        #pragma unroll
        for(int kh = 0; kh < 3; kh++)
          #pragma unroll
          for(int kw = 0; kw < 3; kw++)
            a += sX[s][kh][S*j + kw] * wv[kh*3 + kw];
        acc[p] = a;
      }
    }
    __syncthreads();
  }

  float bv = ldm(bias, co0 + co, dm);
  long obase = ((long)b*Cout + co0 + co)*Hout*Wout + (long)ho*Wout + g*SEG;
  #pragma unroll
  for(int p = 0; p < SEG; p++) stm(out, obase + p, fout, acc[p] + bv);
}

// ---------------- InstanceNorm (affine=False) + PReLU, in place ----------------
__global__ void k_inorm_prelu(void* __restrict__ x, int f, int HW,
                              const void* __restrict__ a, const int* __restrict__ dmode)
{
  int dm = *dmode;
  long base = (long)blockIdx.x * HW;
  float s = 0.f, s2 = 0.f;
  for(int i = threadIdx.x; i < HW; i += 256){ float v = ldm(x, base + i, f); s += v; s2 += v*v; }
  __shared__ float sh[256], sh2[256];
  sh[threadIdx.x] = s; sh2[threadIdx.x] = s2; __syncthreads();
  for(int off = 128; off > 0; off >>= 1){
    if(threadIdx.x < off){ sh[threadIdx.x] += sh[threadIdx.x+off]; sh2[threadIdx.x] += sh2[threadIdx.x+off]; }
    __syncthreads();
  }
  float mean = sh[0] / HW;
  float var  = sh2[0] / HW - mean * mean;
  float inv  = rsqrtf(fmaxf(var, 0.f) + 1e-5f);
  float alpha = ldm(a, 0, dm);
  for(int i = threadIdx.x; i < HW; i += 256){
    float v = (ldm(x, base + i, f) - mean) * inv;
    stm(x, base + i, f, v >= 0.f ? v : alpha * v);
  }
}

// ---------------- transpose [B,C,N] -> [B,N,C] (fp32) ----------------
__global__ void k_transpose(const float* __restrict__ in, float* __restrict__ out, int B, int C, int N){
  long idx = (long)blockIdx.x * 256 + threadIdx.x;
  long total = (long)B * C * N; if(idx >= total) return;
  int c = (int)(idx % C); long t = idx / C; int n = (int)(t % N); int b = (int)(t / N);
  out[idx] = in[((long)b * C + c) * N + n];
}

// ---------------- degree ----------------
__global__ void k_deg(const int* __restrict__ tgt, float* __restrict__ deg, int E){
  int e = blockIdx.x * 256 + threadIdx.x;
  if(e < E) atomicAdd(&deg[tgt[e]], 1.0f);
}

// ---------------- scatter add: agg[b,tgt,c] += x[b,src,c]  ([B,N,C] fp32) ----------------
__global__ void k_scatter(const float* __restrict__ xT, const int* __restrict__ src,
                          const int* __restrict__ tgt, float* __restrict__ agg,
                          int E, int C, int N, int B)
{
  int t = blockIdx.x * 256 + threadIdx.x;
  if(t >= E * C) return;
  int c = t % C; int e = t / C;
  int s = src[e], d = tgt[e];
  for(int b = 0; b < B; b++){
    atomicAdd(&agg[((long)b * N + d) * C + c], xT[((long)b * N + s) * C + c]);
  }
}

// ---------------- SAGE as tiled GEMM ----------------
#define TN 5
__global__ void k_sage2(const float* __restrict__ xT, const float* __restrict__ agg,
                        const float* __restrict__ deg,
                        const float* __restrict__ wlT, const float* __restrict__ wrT,
                        const void* __restrict__ bl,
                        float* __restrict__ out, const int* __restrict__ dmode,
                        int B, int N, int C, int transpose_out)
{
  int o  = threadIdx.x;
  int n0 = blockIdx.x * TN;
  int b  = blockIdx.y;
  __shared__ float sX[TN][256];
  __shared__ float sA[TN][256];
  #pragma unroll
  for(int j = 0; j < TN; j++){
    int n = n0 + j;
    float dinv = 1.0f / fmaxf(deg[n], 1.0f);
    long base = ((long)b * N + n) * C;
    sX[j][o] = xT[base + o];
    sA[j][o] = agg[base + o] * dinv;
  }
  __syncthreads();
  int dm = *dmode;
  float bv = ldm(bl, o, dm);
  float acc[TN];
  #pragma unroll
  for(int j = 0; j < TN; j++) acc[j] = bv;
  #pragma unroll 4
  for(int c = 0; c < 256; c++){
    float wlv = wlT[(long)c * 256 + o];
    float wrv = wrT[(long)c * 256 + o];
    #pragma unroll
    for(int j = 0; j < TN; j++){
      acc[j] += sA[j][c] * wlv + sX[j][c] * wrv;
    }
  }
  #pragma unroll
  for(int j = 0; j < TN; j++){
    int n = n0 + j;
    float v = fmaxf(acc[j], 0.f);
    if(transpose_out) out[((long)b * C + o) * N + n] = v;
    else              out[((long)b * N + n) * C + o] = v;
  }
}

// ---------------- ConvTranspose2d k=3 s=2 p=1 op=1 — full-width tiles ----------------
// launch_bounds(256,2): VGPR cap ~256 so acc[ROWS][SEG][4] stays in registers
// (round-9 default cap of 64 spilled to scratch -> 2.97 GB HBM write traffic).
template<int COT, int ROWS, int SEG, int CC>
__global__ __launch_bounds__(256, 2)
void k_convT5(const void* __restrict__ inA, int fA, int C1,
              const void* __restrict__ inB, int fB, int C2,
              const bf16* __restrict__ wT, const void* __restrict__ bias,
              void* __restrict__ out, int fout,
              const int* __restrict__ dmode,
              int Hin, int Win, int Cout)
{
  constexpr int NG = 256 / COT;
  constexpr int PC = NG * SEG + 1;
  __shared__ float sX[CC][ROWS+1][PC];
  int tid = threadIdx.x;
  int co = tid % COT;
  int g  = tid / COT;
  int i0 = blockIdx.x * ROWS;
  int co0 = blockIdx.y * COT;
  int b  = blockIdx.z;
  int dm = *dmode;
  int Cin = C1 + C2;
  int Wout = 2 * Win;

  float acc[ROWS][SEG][4];
  #pragma unroll
  for(int r = 0; r < ROWS; r++)
    #pragma unroll
    for(int p = 0; p < SEG; p++){
      acc[r][p][0]=0.f; acc[r][p][1]=0.f; acc[r][p][2]=0.f; acc[r][p][3]=0.f;
    }

  for(int ci0 = 0; ci0 < Cin; ci0 += CC){
    for(int e = tid; e < CC*(ROWS+1)*PC; e += 256){
      int s = e / ((ROWS+1)*PC); int rem = e % ((ROWS+1)*PC);
      int r = rem / PC, c = rem % PC;
      int ci = ci0 + s;
      int ii = i0 + r;
      float v = 0.f;
      if(ii < Hin && c < Win){
        v = (ci < C1) ? ldm(inA, ((long)b*C1 + ci)*Hin*Win + (long)ii*Win + c, fA)
                      : ldm(inB, ((long)b*C2 + (ci-C1))*Hin*Win + (long)ii*Win + c, fB);
      }
      sX[s][r][c] = v;
    }
    __syncthreads();
    for(int s = 0; s < CC; s++){
      int ci = ci0 + s;
      float wv[9];
      #pragma unroll
      for(int k = 0; k < 9; k++) wv[k] = bf(wT[((long)ci*9 + k)*Cout + co0 + co]);
      #pragma unroll
      for(int r = 0; r < ROWS; r++){
        float x0[SEG+1], x1[SEG+1];
        #pragma unroll
        for(int c = 0; c <= SEG; c++){
          x0[c] = sX[s][r][g*SEG + c];
          x1[c] = sX[s][r+1][g*SEG + c];
        }
        #pragma unroll
        for(int p = 0; p < SEG; p++){
          float a00 = x0[p], a01 = x0[p+1], a10 = x1[p], a11 = x1[p+1];
          acc[r][p][0] += a00*wv[4];
          acc[r][p][1] += a00*wv[5] + a01*wv[3];
          acc[r][p][2] += a00*wv[7] + a10*wv[1];
          acc[r][p][3] += a00*wv[8] + a01*wv[6] + a10*wv[2] + a11*wv[0];
        }
      }
    }
    __syncthreads();
  }

  float bv = ldm(bias, co0 + co, dm);
  #pragma unroll
  for(int r = 0; r < ROWS; r++){
    int i = i0 + r;
    if(i >= Hin) continue;
    #pragma unroll
    for(int p = 0; p < SEG; p++){
      int j = g*SEG + p;
      if(j >= Win) continue;
      long base = (((long)b*Cout + co0 + co)*2*Hin + 2*i)*Wout + 2*j;
      stm(out, base,            fout, acc[r][p][0] + bv);
      stm(out, base + 1,        fout, acc[r][p][1] + bv);
      stm(out, base + Wout,     fout, acc[r][p][2] + bv);
      stm(out, base + Wout + 1, fout, acc[r][p][3] + bv);
    }
  }
}

// ---------------- u4 special: Cout=2, thread-per-input-pixel ----------------
__global__ __launch_bounds__(256, 2)
void k_convT4(const void* __restrict__ inA, int fA,
              const void* __restrict__ inB, int fB,
              const void* __restrict__ w, const void* __restrict__ bias,
              void* __restrict__ out, long out_off, int fout_sel,
              const int* __restrict__ dmode,
              int Hin, int Win)
{
  __shared__ float sW[64*2*9];
  __shared__ float sB[2];
  int tid = threadIdx.x;
  int dm = *dmode;
  for(int e = tid; e < 64*2*9; e += 256) sW[e] = ldm(w, e, dm);
  if(tid < 2) sB[tid] = ldm(bias, tid, dm);
  __syncthreads();
  int i = blockIdx.x, b = blockIdx.z;
  int j = tid;
  if(j >= Win) return;
  float acc[2][4];
  #pragma unroll
  for(int co = 0; co < 2; co++){ acc[co][0]=0.f; acc[co][1]=0.f; acc[co][2]=0.f; acc[co][3]=0.f; }
  for(int ci = 0; ci < 64; ci++){
    const void* src = (ci < 32) ? inA : inB;
    int f = (ci < 32) ? fA : fB;
    int cc = ci & 31;
    long base = ((long)b*32 + cc)*Hin*Win + (long)i*Win + j;
    float a00 = ldm(src, base, f);
    float a01 = (j+1 < Win) ? ldm(src, base+1, f) : 0.f;
    float a10 = (i+1 < Hin) ? ldm(src, base+Win, f) : 0.f;
    float a11 = (i+1 < Hin && j+1 < Win) ? ldm(src, base+Win+1, f) : 0.f;
    #pragma unroll
    for(int co = 0; co < 2; co++){
      const float* wv = &sW[(ci*2 + co)*9];
      acc[co][0] += a00*wv[4];
      acc[co][1] += a00*wv[5] + a01*wv[3];
      acc[co][2] += a00*wv[7] + a10*wv[1];
      acc[co][3] += a00*wv[8] + a01*wv[6] + a10*wv[2] + a11*wv[0];
    }
  }
  int fout = (fout_sel == 2) ? dm : fout_sel;
  int Wout = 2*Win;
  #pragma unroll
  for(int co = 0; co < 2; co++){
    long base = out_off + (((long)b*2 + co)*2*Hin + 2*i)*Wout + 2*j;
    stm(out, base,          fout, acc[co][0] + sB[co]);
    stm(out, base + 1,      fout, acc[co][1] + sB[co]);
    stm(out, base + Wout,   fout, acc[co][2] + sB[co]);
    stm(out, base + Wout+1, fout, acc[co][3] + sB[co]);
  }
}

static inline int cdiv(long a, long b){ return (int)((a + b - 1) / b); }

extern "C" void kernel_launch(void* const* d_in, const int* in_sizes, int n_in,
                              void* d_out, int out_size, void* d_ws, size_t ws_size,
                              hipStream_t stream) {
  const void* x_in  = d_in[0];
  const int*  edges = (const int*)d_in[1];
  const int* src = edges;          // edges[0,:]
  const int* tgt = edges + 5000;   // edges[1,:]
  const void *w_d4=d_in[2],  *b_d4=d_in[3],  *a_d4=d_in[4];
  const void *w_d3=d_in[5],  *b_d3=d_in[6],  *a_d3=d_in[7];
  const void *w_d2=d_in[8],  *b_d2=d_in[9],  *a_d2=d_in[10];
  const void *w_d1=d_in[11], *b_d1=d_in[12], *a_d1=d_in[13];
  const void *w_bot=d_in[14],*b_bot=d_in[15],*a_bot=d_in[16];
  const void *wl1=d_in[17], *bl1=d_in[18], *wr1=d_in[19];
  const void *wl2=d_in[20], *bl2=d_in[21], *wr2=d_in[22];
  const void *w_u1=d_in[23], *b_u1=d_in[24], *a_u1=d_in[25];
  const void *w_u2=d_in[26], *b_u2=d_in[27], *a_u2=d_in[28];
  const void *w_u3=d_in[29], *b_u3=d_in[30], *a_u3=d_in[31];
  const void *w_u4=d_in[32], *b_u4=d_in[33];

  const int NNODE = 625, E = 5000, CG = 256;

  // tail: deg/mode (4KB) + 4 sage wT fp32 (1MB) + convT wT bf16 (1.55MB)
  const long TAIL = 4096 + 4*262144L + (589824L + 147456L + 36864L) * 2;
  // encoder wT (bf16): d3 18432 + d2 73728 + d1 294912 + bot 589824 + d4 288 = 977184 el
  const long ENCW = 977184L * 2;
  int Bc = 16;
  while(Bc > 1 && (7680000L * Bc + TAIL) > (long)ws_size) Bc >>= 1;
  int enc_in_pool = (Bc >= 8);   // pool free-gap holds 320000*Bc bytes >= ENCW iff Bc>=8
  if(!enc_in_pool){
    Bc = 16;
    while(Bc > 1 && (7680000L * Bc + TAIL + ENCW) > (long)ws_size) Bc >>= 1;
  }

  char* wsb = (char*)d_ws;
  long o_xs1  = 2560000L * Bc;
  long o_BIGA = 3840000L * Bc;
  long o_BIGB = 6400000L * Bc;
  long o_deg  = 7680000L * Bc;
  bf16*  xs0 = (bf16*)wsb;                             // [d4 -> u4]
  bf16*  xs1 = (bf16*)(wsb + o_xs1);                   // [d3 -> u3]
  bf16*  xs2 = (bf16*)(wsb + o_BIGA);                  // [d2 -> u2]
  bf16*  xs3 = (bf16*)(wsb + o_BIGA +  640000L*Bc);    // [d1 -> u1]
  float* bot = (float*)(wsb + o_BIGA +  960000L*Bc);   // [bot -> u1] (=g2)
  float* xT  = (float*)(wsb + o_BIGA + 1600000L*Bc);   // [tr -> sage1]
  bf16*  u1  = (bf16*)(wsb + o_BIGA + 1600000L*Bc);    // alias xT (dead)
  bf16*  u3  = (bf16*)(wsb + o_BIGA);                  // alias BIGA (dead)
  float* agg = (float*)(wsb + o_BIGB);
  float* g1  = (float*)(wsb + o_BIGB +  640000L*Bc);   // [sage1 -> sage2]
  bf16*  u2  = (bf16*)(wsb + o_BIGB);                  // alias agg+g1 (dead)
  float* deg = (float*)(wsb + o_deg);                  // 625 fp32
  int*  mode = (int*)(wsb + o_deg + 3072);
  float* wlT1 = (float*)(wsb + o_deg + 4096);          // 4 x 65536 fp32
  float* wrT1 = wlT1 + 65536;
  float* wlT2 = wrT1 + 65536;
  float* wrT2 = wlT2 + 65536;
  bf16*  wTu1 = (bf16*)(wrT2 + 65536);                 // 512*128*9 bf16
  bf16*  wTu2 = wTu1 + 589824;                         // 256*64*9
  bf16*  wTu3 = wTu2 + 147456;                         // 128*32*9
  // encoder weights: pool free-gap [BIGA+2240000*Bc, BIGA+2560000*Bc) when Bc>=8
  bf16*  wTd3 = enc_in_pool ? (bf16*)(wsb + o_BIGA + 2240000L*Bc) : (wTu3 + 36864);
  bf16*  wTd2 = wTd3 + 18432;
  bf16*  wTd1 = wTd2 + 73728;
  bf16*  wTdB = wTd1 + 294912;
  bf16*  wTd4 = wTdB + 589824;
  float* g2  = bot;

  hipLaunchKernelGGL(k_detect, dim3(1), dim3(1), 0, stream, w_d4, mode);

  hipMemsetAsync(deg, 0, NNODE*sizeof(float), stream);
  hipLaunchKernelGGL(k_deg, dim3(cdiv(E,256)), dim3(256), 0, stream, tgt, deg, E);
  hipLaunchKernelGGL(k_wtrans, dim3(256), dim3(256), 0, stream, wl1, wlT1, mode, CG);
  hipLaunchKernelGGL(k_wtrans, dim3(256), dim3(256), 0, stream, wr1, wrT1, mode, CG);
  hipLaunchKernelGGL(k_wtrans, dim3(256), dim3(256), 0, stream, wl2, wlT2, mode, CG);
  hipLaunchKernelGGL(k_wtrans, dim3(256), dim3(256), 0, stream, wr2, wrT2, mode, CG);
  hipLaunchKernelGGL(k_wtrans2, dim3(cdiv(589824,256)), dim3(256), 0, stream, w_u1, wTu1, mode, 512, 128);
  hipLaunchKernelGGL(k_wtrans2, dim3(cdiv(147456,256)), dim3(256), 0, stream, w_u2, wTu2, mode, 256, 64);
  hipLaunchKernelGGL(k_wtrans2, dim3(cdiv(36864,256)),  dim3(256), 0, stream, w_u3, wTu3, mode, 128, 32);

  for(int bo = 0; bo < 16; bo += Bc){
    long x_off   = (long)bo * 160000;
    long out_off = (long)bo * 320000;

    // encoder weight transposes (pool region may be clobbered by decoder -> per chunk)
    hipLaunchKernelGGL(k_wtrans3, dim3(cdiv(18432,256)),  dim3(256), 0, stream, w_d3, wTd3, mode, 32, 64);
    hipLaunchKernelGGL(k_wtrans3, dim3(cdiv(73728,256)),  dim3(256), 0, stream, w_d2, wTd2, mode, 64, 128);
    hipLaunchKernelGGL(k_wtrans3, dim3(cdiv(294912,256)), dim3(256), 0, stream, w_d1, wTd1, mode, 128, 256);
    hipLaunchKernelGGL(k_wtrans3, dim3(cdiv(589824,256)), dim3(256), 0, stream, w_bot, wTdB, mode, 256, 256);
    hipLaunchKernelGGL(k_wtrans3, dim3(cdiv(288,256)),    dim3(256), 0, stream, w_d4, wTd4, mode, 1, 32);

    // ---- encoder (full-width row tiles) ----
    hipLaunchKernelGGL((k_conv6<32,25,1,2,402>), dim3(200, 1, Bc), dim3(256), 0, stream,
                       x_in, x_off, 2, wTd4, b_d4, xs0, 0, mode, 1, 400, 400, 32, 200, 200);
    hipLaunchKernelGGL(k_inorm_prelu, dim3(Bc*32), dim3(256), 0, stream, xs0, 0, 40000, a_d4, mode);
    hipLaunchKernelGGL((k_conv6<64,25,4,2,202>), dim3(100, 1, Bc), dim3(256), 0, stream,
                       xs0, 0L, 0, wTd3, b_d3, xs1, 0, mode, 32, 200, 200, 64, 100, 100);
    hipLaunchKernelGGL(k_inorm_prelu, dim3(Bc*64), dim3(256), 0, stream, xs1, 0, 10000, a_d3, mode);
    hipLaunchKernelGGL((k_conv6<128,25,8,2,102>), dim3(50, 1, Bc), dim3(256), 0, stream,
                       xs1, 0L, 0, wTd2, b_d2, xs2, 0, mode, 64, 100, 100, 128, 50, 50);
    hipLaunchKernelGGL(k_inorm_prelu, dim3(Bc*128), dim3(256), 0, stream, xs2, 0, 2500, a_d2, mode);
    hipLaunchKernelGGL((k_conv6<256,25,8,2,52>), dim3(25, 1, Bc), dim3(256), 0, stream,
                       xs2, 0L, 0, wTd1, b_d1, xs3, 0, mode, 128, 50, 50, 256, 25, 25);
    hipLaunchKernelGGL(k_inorm_prelu, dim3(Bc*256), dim3(256), 0, stream, xs3, 0, 625, a_d1, mode);
    hipLaunchKernelGGL((k_conv6<256,25,8,1,28>), dim3(25, 1, Bc), dim3(256), 0, stream,
                       xs3, 0L, 0, wTdB, b_bot, bot, 1, mode, 256, 25, 25, 256, 25, 25);
    hipLaunchKernelGGL(k_inorm_prelu, dim3(Bc*256), dim3(256), 0, stream, bot, 1, 625, a_bot, mode);

    // ---- GNN ----
    { long n = (long)Bc*CG*NNODE;
      hipLaunchKernelGGL(k_transpose, dim3(cdiv(n,256)), dim3(256), 0, stream, bot, xT, Bc, CG, NNODE); }
    hipMemsetAsync(agg, 0, 640000L*Bc, stream);
    hipLaunchKernelGGL(k_scatter, dim3(cdiv((long)E*CG,256)), dim3(256), 0, stream, xT, src, tgt, agg, E, CG, NNODE, Bc);
    hipLaunchKernelGGL(k_sage2, dim3(125, Bc), dim3(256), 0, stream,
                       xT, agg, deg, wlT1, wrT1, bl1, g1, mode, Bc, NNODE, CG, 0);
    hipMemsetAsync(agg, 0, 640000L*Bc, stream);
    hipLaunchKernelGGL(k_scatter, dim3(cdiv((long)E*CG,256)), dim3(256), 0, stream, g1, src, tgt, agg, E, CG, NNODE, Bc);
    hipLaunchKernelGGL(k_sage2, dim3(125, Bc), dim3(256), 0, stream,
                       g1, agg, deg, wlT2, wrT2, bl2, g2, mode, Bc, NNODE, CG, 1);

    // ---- decoder (full-width-tile convT) ----
    hipLaunchKernelGGL((k_convT5<32,5,4,8>), dim3(5, 4, Bc), dim3(256), 0, stream,
                       xs3, 0, 256, g2, 1, 256, wTu1, b_u1, u1, 0, mode, 25, 25, 128);
    hipLaunchKernelGGL(k_inorm_prelu, dim3(Bc*128), dim3(256), 0, stream, u1, 0, 2500, a_u1, mode);
    hipLaunchKernelGGL((k_convT5<32,2,7,8>), dim3(25, 2, Bc), dim3(256), 0, stream,
                       xs2, 0, 128, u1, 0, 128, wTu2, b_u2, u2, 0, mode, 50, 50, 64);
    hipLaunchKernelGGL(k_inorm_prelu, dim3(Bc*64), dim3(256), 0, stream, u2, 0, 10000, a_u2, mode);
    hipLaunchKernelGGL((k_convT5<32,1,13,8>), dim3(100, 1, Bc), dim3(256), 0, stream,
                       xs1, 0, 64, u2, 0, 64, wTu3, b_u3, u3, 0, mode, 100, 100, 32);
    hipLaunchKernelGGL(k_inorm_prelu, dim3(Bc*32), dim3(256), 0, stream, u3, 0, 40000, a_u3, mode);
    hipLaunchKernelGGL(k_convT4, dim3(200, 1, Bc), dim3(256), 0, stream,
                       xs0, 0, u3, 0, w_u4, b_u4, d_out, out_off, 2, mode, 200, 200);
  }
}